// Round 7
// baseline (1821.485 us; speedup 1.0000x reference)
//
#include <hip/hip_runtime.h>
#include <hip/hip_bf16.h>

// SliceAttention on MI355X — round 10 (= round-8 plan, clean single-block).
// GEMM: round-7 parity-paired 3-term structure (52% MfmaUtil) + read-order
// tweak. k_staged_bf: W rows wave-uniform -> uniform global reads + O in
// registers, no LDS. k_smax: lane=m remap; xv slice wave-uniform from global.

#define NTOK 32768   // B*N
#define HH   1024
#define NHD  16
#define DD   64

typedef short short8 __attribute__((ext_vector_type(8)));
typedef float f32x4 __attribute__((ext_vector_type(4)));

#define AS1 __attribute__((address_space(1)))
#define AS3 __attribute__((address_space(3)))

__device__ __forceinline__ void glds16(const void* g, void* l) {
  __builtin_amdgcn_global_load_lds((const AS1 void*)g, (AS3 void*)l, 16, 0, 0);
}

__device__ __forceinline__ void split1(float v, __hip_bfloat16& h, __hip_bfloat16& l) {
  h = __float2bfloat16(v);
  l = __float2bfloat16(v - __bfloat162float(h));
}

// =================== fast-path builders ===================

// AcatT rows 0..1023 of WbT: WbT[h*64+m][k] = sum_d w_kv[k][h*64+d]*xq[h][m][d]
__global__ __launch_bounds__(256) void k_acat_t(const float* __restrict__ w_kv,
                                                const float* __restrict__ xq,
                                                __hip_bfloat16* __restrict__ wbth,
                                                __hip_bfloat16* __restrict__ wbtl) {
  int hd = blockIdx.x >> 3, kt = blockIdx.x & 7, k0 = kt * 128;
  __shared__ float xqs[64 * 65];
  __shared__ float wks[128 * 65];
  int t = threadIdx.x;
  for (int j = 0; j < 16; ++j) {
    int idx = t + 256 * j; int m = idx >> 6, d = idx & 63;
    xqs[m * 65 + d] = xq[hd * 4096 + idx];
  }
  for (int j = 0; j < 32; ++j) {
    int idx = t + 256 * j; int r = idx >> 6, c = idx & 63;
    wks[r * 65 + c] = w_kv[(size_t)(k0 + r) * 2048 + hd * 64 + c];
  }
  __syncthreads();
  int m = t & 63, kg = t >> 6;
  __hip_bfloat16 hbuf[32], lbuf[32];
  for (int i = 0; i < 32; ++i) {
    int k = kg * 32 + i;
    float s = 0.f;
    #pragma unroll 8
    for (int d = 0; d < 64; ++d) s = fmaf(wks[k * 65 + d], xqs[m * 65 + d], s);
    split1(s, hbuf[i], lbuf[i]);
  }
  size_t o = (size_t)(hd * 64 + m) * 1024 + k0 + kg * 32;
  for (int i = 0; i < 32; i += 8) {
    *(uint4*)&wbth[o + i] = *(uint4*)&hbuf[i];
    *(uint4*)&wbtl[o + i] = *(uint4*)&lbuf[i];
  }
}

// transpose + split a 1024x1024 fp32 block: dst[c][r] = src[r*ld + c]
__global__ __launch_bounds__(256) void k_tsplit(const float* __restrict__ src, int ld,
                                                __hip_bfloat16* __restrict__ dh,
                                                __hip_bfloat16* __restrict__ dl) {
  __shared__ float tile[64 * 65];
  int br = blockIdx.y * 64, bc = blockIdx.x * 64;
  int t = threadIdx.x;
  for (int j = 0; j < 16; ++j) {
    int idx = t + 256 * j; int r = idx >> 6, c = idx & 63;
    tile[r * 65 + c] = src[(size_t)(br + r) * ld + bc + c];
  }
  __syncthreads();
  for (int j = 0; j < 16; ++j) {
    int idx = t + 256 * j; int c = idx >> 6, r = idx & 63;
    float v = tile[r * 65 + c];
    __hip_bfloat16 hv, lv; split1(v, hv, lv);
    size_t o = (size_t)(bc + c) * 1024 + br + r;
    dh[o] = hv; dl[o] = lv;
  }
}

// split contiguous fp32 -> bf16 hi/lo (8 elems/thread)
__global__ void k_split(const float* __restrict__ src, __hip_bfloat16* __restrict__ hi,
                        __hip_bfloat16* __restrict__ lo) {
  size_t base = ((size_t)blockIdx.x * 256 + threadIdx.x) * 8;
  float4 v0 = *(const float4*)&src[base];
  float4 v1 = *(const float4*)&src[base + 4];
  float vv[8] = {v0.x, v0.y, v0.z, v0.w, v1.x, v1.y, v1.z, v1.w};
  __hip_bfloat16 h8[8], l8[8];
  #pragma unroll
  for (int i = 0; i < 8; ++i) split1(vv[i], h8[i], l8[i]);
  *(uint4*)&hi[base] = *(uint4*)h8;
  *(uint4*)&lo[base] = *(uint4*)l8;
}

// =================== parity-paired 3-term 256x256 MFMA NT GEMM =============
// C[M,N] = (Ah+Al)·(Bh+Bl)^T + bias ~= AhBh + AhBl + AlBh.
// 512 thr = 8 waves (2M x 4N), per-wave 128x64 out, BK=32, 64 virtual tiles:
// v=2k -> {Ah,Bh}[k], v=2k+1 -> {Al,Bl}[k] (ah/bh regs carried).
// 4 x 32KB LDS rotation, stage(v+3)/tile (4 glds16), vmcnt(8) once/tile,
// ONE s_barrier/tile. T2 swizzle verified conflicts=0 (rounds 5-7).
__global__ __launch_bounds__(512, 2) void k_mfma8(
    const __hip_bfloat16* __restrict__ Ah, const __hip_bfloat16* __restrict__ Al,
    const __hip_bfloat16* __restrict__ Bh, const __hip_bfloat16* __restrict__ Bl,
    const float* __restrict__ bias, float* __restrict__ C, int ldc) {
  __shared__ __align__(16) char lds[131072];
  const int t = threadIdx.x;
  const int w = t >> 6, lane = t & 63;

  const int gx = gridDim.x;
  const int nwg = gx * gridDim.y;
  const int bid = blockIdx.y * gx + blockIdx.x;
  const int swzb = (bid & 7) * (nwg >> 3) + (bid >> 3);
  const int n0 = (swzb % gx) * 256;
  const int m0 = (swzb / gx) * 256;

  const int wr = w >> 2, wc = w & 3;
  const int fm = lane & 15, kq = lane >> 4;

  int offA[8], offB[4];
  #pragma unroll
  for (int i = 0; i < 8; ++i) {
    int row = wr * 128 + i * 16 + fm;
    offA[i] = (row >> 1) * 128 + ((((row & 1) << 2) | kq) ^ ((row >> 1) & 7)) * 16;
  }
  #pragma unroll
  for (int j = 0; j < 4; ++j) {
    int row = wc * 64 + j * 16 + fm;
    offB[j] = (row >> 1) * 128 + ((((row & 1) << 2) | kq) ^ ((row >> 1) & 7)) * 16;
  }

  const int sp = lane >> 3, su = (lane & 7) ^ sp;
  const int srow = 2 * sp + (su >> 2);
  const int scol = (su & 3) * 8;
  const int aO0 = (m0 + w * 16 + srow) * 1024 + scol;
  const int aO1 = aO0 + 128 * 1024;
  const int bO0 = (n0 + w * 16 + srow) * 1024 + scol;
  const int bO1 = bO0 + 128 * 1024;
  const int ldst = w * 1024 + lane * 16;

  f32x4 acc[8][4];
  #pragma unroll
  for (int i = 0; i < 8; ++i)
    #pragma unroll
    for (int j = 0; j < 4; ++j) acc[i][j] = (f32x4){0.f, 0.f, 0.f, 0.f};

  auto stage = [&](int ts) {
    int koff = (ts >> 1) * 32;
    char* buf = &lds[(ts & 3) * 32768];
    const __hip_bfloat16* As = (ts & 1) ? Al : Ah;
    const __hip_bfloat16* Bs = (ts & 1) ? Bl : Bh;
    glds16(As + aO0 + koff, buf + ldst);
    glds16(As + aO1 + koff, buf + 8192 + ldst);
    glds16(Bs + bO0 + koff, buf + 16384 + ldst);
    glds16(Bs + bO1 + koff, buf + 24576 + ldst);
  };

  stage(0); stage(1); stage(2);
  asm volatile("s_waitcnt vmcnt(8)" ::: "memory");
  __builtin_amdgcn_s_barrier();
  __builtin_amdgcn_sched_barrier(0);

  short8 ah[8], bh[4], xb[4];
  for (int k = 0; k < 32; ++k) {
    const int v0 = 2 * k, v1 = v0 + 1;
    const char* rb0 = &lds[(v0 & 3) * 32768];
    const char* rb1 = &lds[(v1 & 3) * 32768];

    // ==== even tile v0: {Ah,Bh}[k] -> AhBh ====
    int ts0 = v0 + 3; if (ts0 > 63) ts0 = 63;
    #pragma unroll
    for (int j = 0; j < 4; ++j) bh[j] = *(const short8*)(rb0 + 16384 + offB[j]);
    #pragma unroll
    for (int i = 0; i < 8; ++i) ah[i] = *(const short8*)(rb0 + offA[i]);
    stage(ts0);
    __builtin_amdgcn_s_setprio(1);
    #pragma unroll
    for (int i = 0; i < 8; ++i)
      #pragma unroll
      for (int j = 0; j < 4; ++j)
        acc[i][j] = __builtin_amdgcn_mfma_f32_16x16x32_bf16(ah[i], bh[j], acc[i][j], 0, 0, 0);
    __builtin_amdgcn_s_setprio(0);
    asm volatile("s_waitcnt vmcnt(8)" ::: "memory");
    __builtin_amdgcn_s_barrier();
    __builtin_amdgcn_sched_barrier(0);

    // ==== odd tile v1: {Al,Bl}[k] -> AhBl (ah regs) + AlBh (bh regs) ====
    int ts1 = v1 + 3; if (ts1 > 63) ts1 = 63;
    #pragma unroll
    for (int j = 0; j < 4; ++j) xb[j] = *(const short8*)(rb1 + 16384 + offB[j]);
    stage(ts1);
    __builtin_amdgcn_s_setprio(1);
    #pragma unroll
    for (int i = 0; i < 8; ++i)
      #pragma unroll
      for (int j = 0; j < 4; ++j)
        acc[i][j] = __builtin_amdgcn_mfma_f32_16x16x32_bf16(ah[i], xb[j], acc[i][j], 0, 0, 0);
    __builtin_amdgcn_s_setprio(0);
    #pragma unroll
    for (int i = 0; i < 8; ++i) ah[i] = *(const short8*)(rb1 + offA[i]);  // Al
    __builtin_amdgcn_s_setprio(1);
    #pragma unroll
    for (int i = 0; i < 8; ++i)
      #pragma unroll
      for (int j = 0; j < 4; ++j)
        acc[i][j] = __builtin_amdgcn_mfma_f32_16x16x32_bf16(ah[i], bh[j], acc[i][j], 0, 0, 0);
    __builtin_amdgcn_s_setprio(0);
    asm volatile("s_waitcnt vmcnt(8)" ::: "memory");
    __builtin_amdgcn_s_barrier();
    __builtin_amdgcn_sched_barrier(0);
  }

  asm volatile("s_waitcnt vmcnt(0)" ::: "memory");
  __builtin_amdgcn_sched_barrier(0);

  const int cm = (lane >> 4) * 4, cn = lane & 15;
  #pragma unroll
  for (int j = 0; j < 4; ++j) {
    int col = n0 + wc * 64 + j * 16 + cn;
    float bbv = bias[col];
    #pragma unroll
    for (int i = 0; i < 8; ++i) {
      int row = m0 + wr * 128 + i * 16 + cm;
      f32x4 v = acc[i][j];
      #pragma unroll
      for (int r = 0; r < 4; ++r)
        C[(size_t)(row + r) * ldc + col] = v[r] + bbv;
    }
  }
}

// =================== fallback builders (round-2) ===================
__global__ __launch_bounds__(256) void k_acat(const float* __restrict__ w_kv,
                                              const float* __restrict__ xq,
                                              float* __restrict__ wbig) {
  int h = blockIdx.x >> 3, kt = blockIdx.x & 7, k0 = kt * 128;
  __shared__ float xqs[64 * 68];
  __shared__ float wks[128 * 68];
  int t = threadIdx.x;
  for (int j = 0; j < 16; ++j) {
    int idx = t + 256 * j; int m = idx >> 6, d = idx & 63;
    xqs[m * 68 + d] = xq[h * 4096 + idx];
  }
  for (int j = 0; j < 32; ++j) {
    int idx = t + 256 * j; int r = idx >> 6, c = idx & 63;
    wks[r * 68 + c] = w_kv[(k0 + r) * 2048 + h * 64 + c];
  }
  __syncthreads();
  int k = t >> 1, half = t & 1;
  float out[32];
  for (int mi = 0; mi < 32; ++mi) {
    int m = half * 32 + mi;
    float s = 0.f;
    #pragma unroll 8
    for (int d = 0; d < 64; ++d) s = fmaf(wks[k * 68 + d], xqs[m * 68 + d], s);
    out[mi] = s;
  }
  float* dst = &wbig[(k0 + k) * 2048 + h * 64 + half * 32];
  for (int mi = 0; mi < 32; mi += 4)
    *(float4*)(dst + mi) = make_float4(out[mi], out[mi + 1], out[mi + 2], out[mi + 3]);
}

__global__ void k_copyv(const float* __restrict__ w_kv, float* __restrict__ wbig) {
  int idx4 = blockIdx.x * 256 + threadIdx.x;
  int k = idx4 >> 8, j4 = idx4 & 255;
  int off = k * 2048 + 1024 + j4 * 4;
  *(float4*)(wbig + off) = *(const float4*)(w_kv + off);
}

__global__ void k_bias1(const float* __restrict__ xq, const float* __restrict__ b_kv,
                        float* __restrict__ bias1) {
  int j = blockIdx.x * 256 + threadIdx.x;
  if (j < 1024) {
    int h = j >> 6, m = j & 63;
    float s = 0.f;
    for (int d = 0; d < 64; ++d) s = fmaf(xq[h * 4096 + m * 64 + d], b_kv[h * 64 + d], s);
    bias1[j] = s;
  } else {
    bias1[j] = b_kv[j];
  }
}

__global__ __launch_bounds__(256) void k_temp(const float* __restrict__ x,
                                              const float* __restrict__ w_temp,
                                              const float* __restrict__ b_temp,
                                              float* __restrict__ T) {
  __shared__ float xs[16 * 1028];
  int t = threadIdx.x;
  int bn0 = blockIdx.x * 16;
  for (int j = 0; j < 16; ++j) {
    int idx4 = t + 256 * j; int row = idx4 >> 8, c4 = (idx4 & 255) * 4;
    *(float4*)&xs[row * 1028 + c4] = *(const float4*)&x[(bn0 + row) * 1024 + c4];
  }
  __syncthreads();
  int tok = t >> 4, j = t & 15;
  float z = b_temp[j];
  for (int k = 0; k < 1024; ++k) z = fmaf(xs[tok * 1028 + k], w_temp[k * 16 + j], z);
  float sp = fmaxf(z, 0.f) + log1pf(expf(-fabsf(z)));
  T[(bn0 + tok) * 16 + j] = 0.5f + sp;
}

__global__ __launch_bounds__(256) void k_gemm(const float* __restrict__ A, int lda,
                                              const float* __restrict__ Bm, int ldb,
                                              const float* __restrict__ bias,
                                              float* __restrict__ C, int ldc, int K) {
  __shared__ float As[8 * 132];
  __shared__ float Bs[8 * 132];
  int t = threadIdx.x;
  int m0 = blockIdx.y * 128, n0 = blockIdx.x * 128;
  int ar = t >> 1, ac = (t & 1) * 4;
  int bk = t >> 5, bc = (t & 31) * 4;
  const float* Ag = A + (size_t)(m0 + ar) * lda + ac;
  const float* Bg = Bm + (size_t)bk * ldb + n0 + bc;
  int tx = t & 15, ty = t >> 4;
  float acc[8][8] = {};
  float4 a4 = *(const float4*)Ag;
  float4 b4 = *(const float4*)Bg;
  for (int kt = 0; kt < K; kt += 8) {
    __syncthreads();
    As[(ac + 0) * 132 + ar] = a4.x;
    As[(ac + 1) * 132 + ar] = a4.y;
    As[(ac + 2) * 132 + ar] = a4.z;
    As[(ac + 3) * 132 + ar] = a4.w;
    *(float4*)&Bs[bk * 132 + bc] = b4;
    __syncthreads();
    if (kt + 8 < K) {
      a4 = *(const float4*)(Ag + kt + 8);
      b4 = *(const float4*)(Bg + (size_t)(kt + 8) * ldb);
    }
    #pragma unroll
    for (int k = 0; k < 8; ++k) {
      float av[8], bv[8];
      *(float4*)&av[0] = *(float4*)&As[k * 132 + ty * 8];
      *(float4*)&av[4] = *(float4*)&As[k * 132 + ty * 8 + 4];
      *(float4*)&bv[0] = *(float4*)&Bs[k * 132 + tx * 4];
      *(float4*)&bv[4] = *(float4*)&Bs[k * 132 + 64 + tx * 4];
      #pragma unroll
      for (int i = 0; i < 8; ++i)
        #pragma unroll
        for (int j = 0; j < 8; ++j) acc[i][j] = fmaf(av[i], bv[j], acc[i][j]);
    }
  }
  float4 bb0 = *(const float4*)&bias[n0 + tx * 4];
  float4 bb1 = *(const float4*)&bias[n0 + 64 + tx * 4];
  #pragma unroll
  for (int i = 0; i < 8; ++i) {
    float* crow = C + (size_t)(m0 + ty * 8 + i) * ldc + n0;
    float4 o0 = make_float4(acc[i][0] + bb0.x, acc[i][1] + bb0.y,
                            acc[i][2] + bb0.z, acc[i][3] + bb0.w);
    float4 o1 = make_float4(acc[i][4] + bb1.x, acc[i][5] + bb1.y,
                            acc[i][6] + bb1.z, acc[i][7] + bb1.w);
    *(float4*)&crow[tx * 4] = o0;
    *(float4*)&crow[64 + tx * 4] = o1;
  }
}

// ------------- stage B: in-place softmax over m + token/norm accumulation ----
// round-10: lane=m / wave=dg remap. sm read is stride-1 conflict-free; the xv
// slice is wave-uniform -> read from global SX (= S+1024, disjoint half,
// separate __restrict__ so it can scalarize). xv LDS tile dropped.
__global__ __launch_bounds__(256) void k_smax(float* __restrict__ S,
                                              const float* __restrict__ SX,
                                              const float* __restrict__ T,
                                              float* __restrict__ token, float* __restrict__ norm) {
  int pair = blockIdx.x >> 3, chunk = blockIdx.x & 7;
  int b = pair >> 4, h = pair & 15;
  __shared__ float sm[128 * 68];
  int t = threadIdx.x;
  int m = t & 63, dg = t >> 6;
  float acc[16] = {};
  float nacc = 0.f;
  for (int s = 0; s < 8; ++s) {
    int bn0 = b * 8192 + chunk * 1024 + s * 128;
    for (int jj = 0; jj < 8; ++jj) {
      int idx4 = t + 256 * jj; int row = idx4 >> 4, c4 = (idx4 & 15) * 4;
      *(float4*)&sm[row * 68 + c4] =
          *(const float4*)&S[(size_t)(bn0 + row) * 2048 + h * 64 + c4];
    }
    __syncthreads();
    if (t < 128) {
      float tt = T[(bn0 + t) * 16 + h];
      float inv = 1.f / tt;
      float* row = &sm[t * 68];
      float mx = -1e30f;
      for (int mm = 0; mm < 64; ++mm) mx = fmaxf(mx, row[mm]);
      float sum = 0.f;
      for (int mm = 0; mm < 64; ++mm) { float e = expf((row[mm] - mx) * inv); row[mm] = e; sum += e; }
      float sinv = 1.f / sum;
      for (int mm = 0; mm < 64; ++mm) row[mm] *= sinv;
    }
    __syncthreads();
    for (int jj = 0; jj < 8; ++jj) {
      int idx4 = t + 256 * jj; int row = idx4 >> 4, c4 = (idx4 & 15) * 4;
      *(float4*)&S[(size_t)(bn0 + row) * 2048 + h * 64 + c4] =
          *(const float4*)&sm[row * 68 + c4];
    }
    for (int n = 0; n < 128; ++n) {
      float w = sm[n * 68 + m];
      if (dg == 0) nacc += w;
      const float4* xr = (const float4*)&SX[(size_t)(bn0 + n) * 2048 + h * 64 + dg * 16];
      float4 v0 = xr[0], v1 = xr[1], v2 = xr[2], v3 = xr[3];
      acc[0]  = fmaf(w, v0.x, acc[0]);  acc[1]  = fmaf(w, v0.y, acc[1]);
      acc[2]  = fmaf(w, v0.z, acc[2]);  acc[3]  = fmaf(w, v0.w, acc[3]);
      acc[4]  = fmaf(w, v1.x, acc[4]);  acc[5]  = fmaf(w, v1.y, acc[5]);
      acc[6]  = fmaf(w, v1.z, acc[6]);  acc[7]  = fmaf(w, v1.w, acc[7]);
      acc[8]  = fmaf(w, v2.x, acc[8]);  acc[9]  = fmaf(w, v2.y, acc[9]);
      acc[10] = fmaf(w, v2.z, acc[10]); acc[11] = fmaf(w, v2.w, acc[11]);
      acc[12] = fmaf(w, v3.x, acc[12]); acc[13] = fmaf(w, v3.y, acc[13]);
      acc[14] = fmaf(w, v3.z, acc[14]); acc[15] = fmaf(w, v3.w, acc[15]);
    }
    __syncthreads();
  }
  int tb = pair * 4096 + m * 64 + dg * 16;
  for (int q = 0; q < 16; ++q) atomicAdd(&token[tb + q], acc[q]);
  if (dg == 0) atomicAdd(&norm[pair * 64 + m], nacc);
}

// ------------- stage C -----------
__global__ __launch_bounds__(256) void k_stagec(const float* __restrict__ token,
                                                const float* __restrict__ norm,
                                                const float* __restrict__ proj,
                                                float* __restrict__ ost) {
  int pair = blockIdx.x; int h = pair & 15;
  __shared__ float st[64 * 68];
  __shared__ float qk[64 * 196];
  int t = threadIdx.x;
  for (int j = 0; j < 16; ++j) {
    int idx = t + 256 * j; int m = idx >> 6, d = idx & 63;
    st[m * 68 + d] = token[pair * 4096 + idx] / (norm[pair * 64 + m] + 1e-5f);
  }
  __syncthreads();
  for (int idx = t; idx < 64 * 192; idx += 256) {
    int m = idx / 192, e = idx % 192;
    float s = 0.f;
    const float* pr = &proj[h * 12288 + e];
    const float* sr = &st[m * 68];
    for (int d = 0; d < 64; ++d) s = fmaf(sr[d], pr[d * 192], s);
    qk[m * 196 + e] = s;
  }
  __syncthreads();
  if (t < 64) {
    const float* q = &qk[t * 196];
    float dots[64];
    float mx = -1e30f;
    for (int d = 0; d < 64; ++d) { dots[d] = q[d] * q[64 + d] * 0.125f; mx = fmaxf(mx, dots[d]); }
    float sum = 0.f;
    for (int d = 0; d < 64; ++d) { dots[d] = expf(dots[d] - mx); sum += dots[d]; }
    float sinv = 1.f / sum;
    for (int d = 0; d < 64; ++d) ost[pair * 4096 + t * 64 + d] = dots[d] * sinv * q[128 + d];
  }
}

// ------------- stage D (fallback: fp32 into S) -----------
__global__ __launch_bounds__(256) void k_staged(float* __restrict__ S, const float* __restrict__ ost) {
  int pair = blockIdx.x >> 6, chunk = blockIdx.x & 63;
  int b = pair >> 4, h = pair & 15;
  __shared__ float ws[128 * 68];
  int t = threadIdx.x;
  int bn0 = b * 8192 + chunk * 128;
  for (int jj = 0; jj < 8; ++jj) {
    int idx4 = t + 256 * jj; int row = idx4 >> 4, c4 = (idx4 & 15) * 4;
    *(float4*)&ws[row * 68 + c4] = *(const float4*)&S[(bn0 + row) * 2048 + h * 64 + c4];
  }
  int d = t & 63, ng = t >> 6;
  float o[64];
  #pragma unroll
  for (int mm = 0; mm < 64; ++mm) o[mm] = ost[pair * 4096 + mm * 64 + d];
  __syncthreads();
  for (int i = 0; i < 32; ++i) {
    int n = ng + 4 * i;
    const float* wr = &ws[n * 68];
    float s = 0.f;
    #pragma unroll
    for (int mm = 0; mm < 64; ++mm) s = fmaf(wr[mm], o[mm], s);
    S[(bn0 + n) * 2048 + 1024 + h * 64 + d] = s;
  }
}

// ------------- stage D (fast): W rows wave-uniform from global, O in regs ---
__global__ __launch_bounds__(256) void k_staged_bf(const float* __restrict__ S,
                                                   const float* __restrict__ ost,
                                                   __hip_bfloat16* __restrict__ oxh,
                                                   __hip_bfloat16* __restrict__ oxl) {
  int pair = blockIdx.x >> 6, chunk = blockIdx.x & 63;
  int b = pair >> 4, hd = pair & 15;
  int t = threadIdx.x;
  int wave = t >> 6, d = t & 63;
  int bn0 = b * 8192 + chunk * 128;
  float o[64];
  #pragma unroll
  for (int mm = 0; mm < 64; ++mm) o[mm] = ost[pair * 4096 + mm * 64 + d];
  for (int i = 0; i < 32; ++i) {
    int n = wave * 32 + i;
    const float4* wrow = (const float4*)&S[(size_t)(bn0 + n) * 2048 + hd * 64];
    float a0 = 0.f, a1 = 0.f, a2 = 0.f, a3 = 0.f;
    #pragma unroll
    for (int mq = 0; mq < 16; ++mq) {
      float4 wv = wrow[mq];
      a0 = fmaf(wv.x, o[mq * 4 + 0], a0);
      a1 = fmaf(wv.y, o[mq * 4 + 1], a1);
      a2 = fmaf(wv.z, o[mq * 4 + 2], a2);
      a3 = fmaf(wv.w, o[mq * 4 + 3], a3);
    }
    float sres = (a0 + a1) + (a2 + a3);
    __hip_bfloat16 hv, lv; split1(sres, hv, lv);
    size_t oo = (size_t)(bn0 + n) * 1024 + hd * 64 + d;
    oxh[oo] = hv; oxl[oo] = lv;
  }
}

extern "C" void kernel_launch(void* const* d_in, const int* in_sizes, int n_in,
                              void* d_out, int out_size, void* d_ws, size_t ws_size,
                              hipStream_t stream) {
  const float* x      = (const float*)d_in[0];
  const float* w_kv   = (const float*)d_in[2];
  const float* b_kv   = (const float*)d_in[3];
  const float* w_temp = (const float*)d_in[4];
  const float* b_temp = (const float*)d_in[5];
  const float* xq     = (const float*)d_in[6];
  const float* proj   = (const float*)d_in[7];
  const float* w_out  = (const float*)d_in[8];
  const float* b_out  = (const float*)d_in[9];
  float* out = (float*)d_out;

  float* ws    = (float*)d_ws;
  float* S     = ws;                       // [32768][2048] fp32
  float* T     = S + 67108864;             // [32768][16]
  float* BIAS1 = T + 524288;               // [2048]
  float* TOKEN = BIAS1 + 2048;             // 262144
  float* NORM  = TOKEN + 262144;           // 4096
  float* OST   = NORM + 4096;              // 262144
  float* FEND  = OST + 262144;
  __hip_bfloat16* WbTh = (__hip_bfloat16*)FEND;   // [2048][1024]
  __hip_bfloat16* WbTl = WbTh + 2097152;          // [2048][1024]
  __hip_bfloat16* WoTh = WbTl + 2097152;          // [1024][1024]
  __hip_bfloat16* WoTl = WoTh + 1048576;          // [1024][1024]
  __hip_bfloat16* XH   = WoTl + 1048576;          // [32768][1024] (reused as out_x hi)
  __hip_bfloat16* XL   = XH + 33554432;           // [32768][1024] (reused as out_x lo)
  const size_t need_fast = 419454976ULL;          // bytes

  hipMemsetAsync(TOKEN, 0, (262144 + 4096) * sizeof(float), stream);
  k_bias1<<<8, 256, 0, stream>>>(xq, b_kv, BIAS1);
  k_temp<<<2048, 256, 0, stream>>>(x, w_temp, b_temp, T);

  if (ws_size >= need_fast) {
    // ---- fast path: parity-paired 3-term 256x256 pipelined MFMA GEMMs ----
    k_acat_t<<<128, 256, 0, stream>>>(w_kv, xq, WbTh, WbTl);
    k_tsplit<<<dim3(16, 16), 256, 0, stream>>>(w_kv + 1024, 2048,
                                               WbTh + 1048576, WbTl + 1048576);
    k_tsplit<<<dim3(16, 16), 256, 0, stream>>>(w_out, 1024, WoTh, WoTl);
    k_split<<<16384, 256, 0, stream>>>(x, XH, XL);
    k_mfma8<<<dim3(8, 128), 512, 0, stream>>>(XH, XL, WbTh, WbTl, BIAS1, S, 2048);
    k_smax<<<512, 256, 0, stream>>>(S, S + 1024, T, TOKEN, NORM);
    k_stagec<<<64, 256, 0, stream>>>(TOKEN, NORM, proj, OST);
    k_staged_bf<<<4096, 256, 0, stream>>>(S, OST, XH, XL);
    k_mfma8<<<dim3(4, 128), 512, 0, stream>>>(XH, XL, WoTh, WoTl, b_out, out, 1024);
  } else {
    // ---- fallback: round-2 fp32 vector GEMMs ----
    float* WBIG = (float*)WbTh;            // [1024][2048] fp32 fits in WbTh+WbTl
    k_acat<<<128, 256, 0, stream>>>(w_kv, xq, WBIG);
    k_copyv<<<1024, 256, 0, stream>>>(w_kv, WBIG);
    k_gemm<<<dim3(16, 256), 256, 0, stream>>>(x, 1024, WBIG, 2048, BIAS1, S, 2048, 1024);
    k_smax<<<512, 256, 0, stream>>>(S, S + 1024, T, TOKEN, NORM);
    k_stagec<<<64, 256, 0, stream>>>(TOKEN, NORM, proj, OST);
    k_staged<<<4096, 256, 0, stream>>>(S, OST);
    k_gemm<<<dim3(8, 256), 256, 0, stream>>>(S + 1024, 2048, w_out, 1024, b_out, out, 1024, 1024);
  }
}

// Round 9
// 1341.665 us; speedup vs baseline: 1.3576x; 1.3576x over previous
//
#include <hip/hip_runtime.h>
#include <hip/hip_bf16.h>

// SliceAttention on MI355X — round 12. Base = round-10 (verified, 1416.7us
// equivalent). GEMM untouched. Register-blocked k_smax accumulation (4m x 16d
// per thread, wave-per-n-quarter, LDS-reduced cross-wave combine) and
// k_staged_bf (2d x 16n per thread): raises FMA-per-DS-instr so both become
// VALU-bound instead of DS-broadcast-bound. Round-11 lesson: launch_bounds
// min-waves beyond the VGPR class forces spill (crash via timeout); at
// acc[8][4] the GEMM is occupancy-locked at 1 block/CU — leave it.

#define NTOK 32768   // B*N
#define HH   1024
#define NHD  16
#define DD   64

typedef short short8 __attribute__((ext_vector_type(8)));
typedef float f32x4 __attribute__((ext_vector_type(4)));

#define AS1 __attribute__((address_space(1)))
#define AS3 __attribute__((address_space(3)))

__device__ __forceinline__ void glds16(const void* g, void* l) {
  __builtin_amdgcn_global_load_lds((const AS1 void*)g, (AS3 void*)l, 16, 0, 0);
}

__device__ __forceinline__ void split1(float v, __hip_bfloat16& h, __hip_bfloat16& l) {
  h = __float2bfloat16(v);
  l = __float2bfloat16(v - __bfloat162float(h));
}

// =================== fast-path builders ===================

// AcatT rows 0..1023 of WbT: WbT[h*64+m][k] = sum_d w_kv[k][h*64+d]*xq[h][m][d]
__global__ __launch_bounds__(256) void k_acat_t(const float* __restrict__ w_kv,
                                                const float* __restrict__ xq,
                                                __hip_bfloat16* __restrict__ wbth,
                                                __hip_bfloat16* __restrict__ wbtl) {
  int hd = blockIdx.x >> 3, kt = blockIdx.x & 7, k0 = kt * 128;
  __shared__ float xqs[64 * 65];
  __shared__ float wks[128 * 65];
  int t = threadIdx.x;
  for (int j = 0; j < 16; ++j) {
    int idx = t + 256 * j; int m = idx >> 6, d = idx & 63;
    xqs[m * 65 + d] = xq[hd * 4096 + idx];
  }
  for (int j = 0; j < 32; ++j) {
    int idx = t + 256 * j; int r = idx >> 6, c = idx & 63;
    wks[r * 65 + c] = w_kv[(size_t)(k0 + r) * 2048 + hd * 64 + c];
  }
  __syncthreads();
  int m = t & 63, kg = t >> 6;
  __hip_bfloat16 hbuf[32], lbuf[32];
  for (int i = 0; i < 32; ++i) {
    int k = kg * 32 + i;
    float s = 0.f;
    #pragma unroll 8
    for (int d = 0; d < 64; ++d) s = fmaf(wks[k * 65 + d], xqs[m * 65 + d], s);
    split1(s, hbuf[i], lbuf[i]);
  }
  size_t o = (size_t)(hd * 64 + m) * 1024 + k0 + kg * 32;
  for (int i = 0; i < 32; i += 8) {
    *(uint4*)&wbth[o + i] = *(uint4*)&hbuf[i];
    *(uint4*)&wbtl[o + i] = *(uint4*)&lbuf[i];
  }
}

// transpose + split a 1024x1024 fp32 block: dst[c][r] = src[r*ld + c]
__global__ __launch_bounds__(256) void k_tsplit(const float* __restrict__ src, int ld,
                                                __hip_bfloat16* __restrict__ dh,
                                                __hip_bfloat16* __restrict__ dl) {
  __shared__ float tile[64 * 65];
  int br = blockIdx.y * 64, bc = blockIdx.x * 64;
  int t = threadIdx.x;
  for (int j = 0; j < 16; ++j) {
    int idx = t + 256 * j; int r = idx >> 6, c = idx & 63;
    tile[r * 65 + c] = src[(size_t)(br + r) * ld + bc + c];
  }
  __syncthreads();
  for (int j = 0; j < 16; ++j) {
    int idx = t + 256 * j; int c = idx >> 6, r = idx & 63;
    float v = tile[r * 65 + c];
    __hip_bfloat16 hv, lv; split1(v, hv, lv);
    size_t o = (size_t)(bc + c) * 1024 + br + r;
    dh[o] = hv; dl[o] = lv;
  }
}

// split contiguous fp32 -> bf16 hi/lo (8 elems/thread)
__global__ void k_split(const float* __restrict__ src, __hip_bfloat16* __restrict__ hi,
                        __hip_bfloat16* __restrict__ lo) {
  size_t base = ((size_t)blockIdx.x * 256 + threadIdx.x) * 8;
  float4 v0 = *(const float4*)&src[base];
  float4 v1 = *(const float4*)&src[base + 4];
  float vv[8] = {v0.x, v0.y, v0.z, v0.w, v1.x, v1.y, v1.z, v1.w};
  __hip_bfloat16 h8[8], l8[8];
  #pragma unroll
  for (int i = 0; i < 8; ++i) split1(vv[i], h8[i], l8[i]);
  *(uint4*)&hi[base] = *(uint4*)h8;
  *(uint4*)&lo[base] = *(uint4*)l8;
}

// =================== parity-paired 3-term 256x256 MFMA NT GEMM =============
// (verified round-10 version; ran clean and passed in the round-7 bench)
__global__ __launch_bounds__(512, 2) void k_mfma8(
    const __hip_bfloat16* __restrict__ Ah, const __hip_bfloat16* __restrict__ Al,
    const __hip_bfloat16* __restrict__ Bh, const __hip_bfloat16* __restrict__ Bl,
    const float* __restrict__ bias, float* __restrict__ C, int ldc) {
  __shared__ __align__(16) char lds[131072];
  const int t = threadIdx.x;
  const int w = t >> 6, lane = t & 63;

  const int gx = gridDim.x;
  const int nwg = gx * gridDim.y;
  const int bid = blockIdx.y * gx + blockIdx.x;
  const int swzb = (bid & 7) * (nwg >> 3) + (bid >> 3);
  const int n0 = (swzb % gx) * 256;
  const int m0 = (swzb / gx) * 256;

  const int wr = w >> 2, wc = w & 3;
  const int fm = lane & 15, kq = lane >> 4;

  int offA[8], offB[4];
  #pragma unroll
  for (int i = 0; i < 8; ++i) {
    int row = wr * 128 + i * 16 + fm;
    offA[i] = (row >> 1) * 128 + ((((row & 1) << 2) | kq) ^ ((row >> 1) & 7)) * 16;
  }
  #pragma unroll
  for (int j = 0; j < 4; ++j) {
    int row = wc * 64 + j * 16 + fm;
    offB[j] = (row >> 1) * 128 + ((((row & 1) << 2) | kq) ^ ((row >> 1) & 7)) * 16;
  }

  const int sp = lane >> 3, su = (lane & 7) ^ sp;
  const int srow = 2 * sp + (su >> 2);
  const int scol = (su & 3) * 8;
  const int aO0 = (m0 + w * 16 + srow) * 1024 + scol;
  const int aO1 = aO0 + 128 * 1024;
  const int bO0 = (n0 + w * 16 + srow) * 1024 + scol;
  const int bO1 = bO0 + 128 * 1024;
  const int ldst = w * 1024 + lane * 16;

  f32x4 acc[8][4];
  #pragma unroll
  for (int i = 0; i < 8; ++i)
    #pragma unroll
    for (int j = 0; j < 4; ++j) acc[i][j] = (f32x4){0.f, 0.f, 0.f, 0.f};

  auto stage = [&](int ts) {
    int koff = (ts >> 1) * 32;
    char* buf = &lds[(ts & 3) * 32768];
    const __hip_bfloat16* As = (ts & 1) ? Al : Ah;
    const __hip_bfloat16* Bs = (ts & 1) ? Bl : Bh;
    glds16(As + aO0 + koff, buf + ldst);
    glds16(As + aO1 + koff, buf + 8192 + ldst);
    glds16(Bs + bO0 + koff, buf + 16384 + ldst);
    glds16(Bs + bO1 + koff, buf + 24576 + ldst);
  };

  stage(0); stage(1); stage(2);
  asm volatile("s_waitcnt vmcnt(8)" ::: "memory");
  __builtin_amdgcn_s_barrier();
  __builtin_amdgcn_sched_barrier(0);

  short8 ah[8], bh[4], xb[4];
  for (int k = 0; k < 32; ++k) {
    const int v0 = 2 * k, v1 = v0 + 1;
    const char* rb0 = &lds[(v0 & 3) * 32768];
    const char* rb1 = &lds[(v1 & 3) * 32768];

    int ts0 = v0 + 3; if (ts0 > 63) ts0 = 63;
    #pragma unroll
    for (int j = 0; j < 4; ++j) bh[j] = *(const short8*)(rb0 + 16384 + offB[j]);
    #pragma unroll
    for (int i = 0; i < 8; ++i) ah[i] = *(const short8*)(rb0 + offA[i]);
    stage(ts0);
    __builtin_amdgcn_s_setprio(1);
    #pragma unroll
    for (int i = 0; i < 8; ++i)
      #pragma unroll
      for (int j = 0; j < 4; ++j)
        acc[i][j] = __builtin_amdgcn_mfma_f32_16x16x32_bf16(ah[i], bh[j], acc[i][j], 0, 0, 0);
    __builtin_amdgcn_s_setprio(0);
    asm volatile("s_waitcnt vmcnt(8)" ::: "memory");
    __builtin_amdgcn_s_barrier();
    __builtin_amdgcn_sched_barrier(0);

    int ts1 = v1 + 3; if (ts1 > 63) ts1 = 63;
    #pragma unroll
    for (int j = 0; j < 4; ++j) xb[j] = *(const short8*)(rb1 + 16384 + offB[j]);
    stage(ts1);
    __builtin_amdgcn_s_setprio(1);
    #pragma unroll
    for (int i = 0; i < 8; ++i)
      #pragma unroll
      for (int j = 0; j < 4; ++j)
        acc[i][j] = __builtin_amdgcn_mfma_f32_16x16x32_bf16(ah[i], xb[j], acc[i][j], 0, 0, 0);
    __builtin_amdgcn_s_setprio(0);
    #pragma unroll
    for (int i = 0; i < 8; ++i) ah[i] = *(const short8*)(rb1 + offA[i]);  // Al
    __builtin_amdgcn_s_setprio(1);
    #pragma unroll
    for (int i = 0; i < 8; ++i)
      #pragma unroll
      for (int j = 0; j < 4; ++j)
        acc[i][j] = __builtin_amdgcn_mfma_f32_16x16x32_bf16(ah[i], bh[j], acc[i][j], 0, 0, 0);
    __builtin_amdgcn_s_setprio(0);
    asm volatile("s_waitcnt vmcnt(8)" ::: "memory");
    __builtin_amdgcn_s_barrier();
    __builtin_amdgcn_sched_barrier(0);
  }

  asm volatile("s_waitcnt vmcnt(0)" ::: "memory");
  __builtin_amdgcn_sched_barrier(0);

  const int cm = (lane >> 4) * 4, cn = lane & 15;
  #pragma unroll
  for (int j = 0; j < 4; ++j) {
    int col = n0 + wc * 64 + j * 16 + cn;
    float bbv = bias[col];
    #pragma unroll
    for (int i = 0; i < 8; ++i) {
      int row = m0 + wr * 128 + i * 16 + cm;
      f32x4 v = acc[i][j];
      #pragma unroll
      for (int r = 0; r < 4; ++r)
        C[(size_t)(row + r) * ldc + col] = v[r] + bbv;
    }
  }
}

// =================== fallback builders (round-2) ===================
__global__ __launch_bounds__(256) void k_acat(const float* __restrict__ w_kv,
                                              const float* __restrict__ xq,
                                              float* __restrict__ wbig) {
  int h = blockIdx.x >> 3, kt = blockIdx.x & 7, k0 = kt * 128;
  __shared__ float xqs[64 * 68];
  __shared__ float wks[128 * 68];
  int t = threadIdx.x;
  for (int j = 0; j < 16; ++j) {
    int idx = t + 256 * j; int m = idx >> 6, d = idx & 63;
    xqs[m * 68 + d] = xq[h * 4096 + idx];
  }
  for (int j = 0; j < 32; ++j) {
    int idx = t + 256 * j; int r = idx >> 6, c = idx & 63;
    wks[r * 68 + c] = w_kv[(k0 + r) * 2048 + h * 64 + c];
  }
  __syncthreads();
  int k = t >> 1, half = t & 1;
  float out[32];
  for (int mi = 0; mi < 32; ++mi) {
    int m = half * 32 + mi;
    float s = 0.f;
    #pragma unroll 8
    for (int d = 0; d < 64; ++d) s = fmaf(wks[k * 68 + d], xqs[m * 68 + d], s);
    out[mi] = s;
  }
  float* dst = &wbig[(k0 + k) * 2048 + h * 64 + half * 32];
  for (int mi = 0; mi < 32; mi += 4)
    *(float4*)(dst + mi) = make_float4(out[mi], out[mi + 1], out[mi + 2], out[mi + 3]);
}

__global__ void k_copyv(const float* __restrict__ w_kv, float* __restrict__ wbig) {
  int idx4 = blockIdx.x * 256 + threadIdx.x;
  int k = idx4 >> 8, j4 = idx4 & 255;
  int off = k * 2048 + 1024 + j4 * 4;
  *(float4*)(wbig + off) = *(const float4*)(w_kv + off);
}

__global__ void k_bias1(const float* __restrict__ xq, const float* __restrict__ b_kv,
                        float* __restrict__ bias1) {
  int j = blockIdx.x * 256 + threadIdx.x;
  if (j < 1024) {
    int h = j >> 6, m = j & 63;
    float s = 0.f;
    for (int d = 0; d < 64; ++d) s = fmaf(xq[h * 4096 + m * 64 + d], b_kv[h * 64 + d], s);
    bias1[j] = s;
  } else {
    bias1[j] = b_kv[j];
  }
}

__global__ __launch_bounds__(256) void k_temp(const float* __restrict__ x,
                                              const float* __restrict__ w_temp,
                                              const float* __restrict__ b_temp,
                                              float* __restrict__ T) {
  __shared__ float xs[16 * 1028];
  int t = threadIdx.x;
  int bn0 = blockIdx.x * 16;
  for (int j = 0; j < 16; ++j) {
    int idx4 = t + 256 * j; int row = idx4 >> 8, c4 = (idx4 & 255) * 4;
    *(float4*)&xs[row * 1028 + c4] = *(const float4*)&x[(bn0 + row) * 1024 + c4];
  }
  __syncthreads();
  int tok = t >> 4, j = t & 15;
  float z = b_temp[j];
  for (int k = 0; k < 1024; ++k) z = fmaf(xs[tok * 1028 + k], w_temp[k * 16 + j], z);
  float sp = fmaxf(z, 0.f) + log1pf(expf(-fabsf(z)));
  T[(bn0 + tok) * 16 + j] = 0.5f + sp;
}

__global__ __launch_bounds__(256) void k_gemm(const float* __restrict__ A, int lda,
                                              const float* __restrict__ Bm, int ldb,
                                              const float* __restrict__ bias,
                                              float* __restrict__ C, int ldc, int K) {
  __shared__ float As[8 * 132];
  __shared__ float Bs[8 * 132];
  int t = threadIdx.x;
  int m0 = blockIdx.y * 128, n0 = blockIdx.x * 128;
  int ar = t >> 1, ac = (t & 1) * 4;
  int bk = t >> 5, bc = (t & 31) * 4;
  const float* Ag = A + (size_t)(m0 + ar) * lda + ac;
  const float* Bg = Bm + (size_t)bk * ldb + n0 + bc;
  int tx = t & 15, ty = t >> 4;
  float acc[8][8] = {};
  float4 a4 = *(const float4*)Ag;
  float4 b4 = *(const float4*)Bg;
  for (int kt = 0; kt < K; kt += 8) {
    __syncthreads();
    As[(ac + 0) * 132 + ar] = a4.x;
    As[(ac + 1) * 132 + ar] = a4.y;
    As[(ac + 2) * 132 + ar] = a4.z;
    As[(ac + 3) * 132 + ar] = a4.w;
    *(float4*)&Bs[bk * 132 + bc] = b4;
    __syncthreads();
    if (kt + 8 < K) {
      a4 = *(const float4*)(Ag + kt + 8);
      b4 = *(const float4*)(Bg + (size_t)(kt + 8) * ldb);
    }
    #pragma unroll
    for (int k = 0; k < 8; ++k) {
      float av[8], bv[8];
      *(float4*)&av[0] = *(float4*)&As[k * 132 + ty * 8];
      *(float4*)&av[4] = *(float4*)&As[k * 132 + ty * 8 + 4];
      *(float4*)&bv[0] = *(float4*)&Bs[k * 132 + tx * 4];
      *(float4*)&bv[4] = *(float4*)&Bs[k * 132 + 64 + tx * 4];
      #pragma unroll
      for (int i = 0; i < 8; ++i)
        #pragma unroll
        for (int j = 0; j < 8; ++j) acc[i][j] = fmaf(av[i], bv[j], acc[i][j]);
    }
  }
  float4 bb0 = *(const float4*)&bias[n0 + tx * 4];
  float4 bb1 = *(const float4*)&bias[n0 + 64 + tx * 4];
  #pragma unroll
  for (int i = 0; i < 8; ++i) {
    float* crow = C + (size_t)(m0 + ty * 8 + i) * ldc + n0;
    float4 o0 = make_float4(acc[i][0] + bb0.x, acc[i][1] + bb0.y,
                            acc[i][2] + bb0.z, acc[i][3] + bb0.w);
    float4 o1 = make_float4(acc[i][4] + bb1.x, acc[i][5] + bb1.y,
                            acc[i][6] + bb1.z, acc[i][7] + bb1.w);
    *(float4*)&crow[tx * 4] = o0;
    *(float4*)&crow[64 + tx * 4] = o1;
  }
}

// ------------- stage B: softmax + register-blocked token/norm accumulation --
// Round-12: accumulation thread tile = 4m x 16d, wave ng owns n in
// [ng*32, ng*32+32). Per n: 1 b128 (w, 4m) + 4 b128 (xv, 16d) vs 64 FMA ->
// VALU-bound (was 5 DS / 16 FMA). Cross-wave partials combined through the
// dead sm/xv LDS region, then 4096 atomics/block.
__global__ __launch_bounds__(256) void k_smax(float* __restrict__ S, const float* __restrict__ T,
                                              float* __restrict__ token, float* __restrict__ norm) {
  int pair = blockIdx.x >> 3, chunk = blockIdx.x & 7;
  int b = pair >> 4, h = pair & 15;
  __shared__ float lsh[17408];          // sm[0..8704) | xv[8704..17408)
  float* sm = lsh;
  float* xv = lsh + 8704;
  int t = threadIdx.x;
  int lane = t & 63, ng = t >> 6;
  int mb = (lane & 15) * 4;             // 4 m values
  int db = (lane >> 4) * 16;            // 16 d values
  f32x4 acc4[4][4];                     // [m][d-quad]
  #pragma unroll
  for (int i = 0; i < 4; ++i)
    #pragma unroll
    for (int q = 0; q < 4; ++q) acc4[i][q] = (f32x4){0.f, 0.f, 0.f, 0.f};
  float nacc[4] = {0.f, 0.f, 0.f, 0.f};
  for (int s = 0; s < 8; ++s) {
    int bn0 = b * 8192 + chunk * 1024 + s * 128;
    for (int jj = 0; jj < 8; ++jj) {
      int idx4 = t + 256 * jj; int row = idx4 >> 4, c4 = (idx4 & 15) * 4;
      int g = (bn0 + row) * 2048 + h * 64 + c4;
      *(float4*)&sm[row * 68 + c4] = *(const float4*)&S[g];
      *(float4*)&xv[row * 68 + c4] = *(const float4*)&S[g + 1024];
    }
    __syncthreads();
    if (t < 128) {
      float tt = T[(bn0 + t) * 16 + h];
      float inv = 1.f / tt;
      float* row = &sm[t * 68];
      float mx = -1e30f;
      for (int mm = 0; mm < 64; ++mm) mx = fmaxf(mx, row[mm]);
      float sum = 0.f;
      for (int mm = 0; mm < 64; ++mm) { float e = expf((row[mm] - mx) * inv); row[mm] = e; sum += e; }
      float sinv = 1.f / sum;
      for (int mm = 0; mm < 64; ++mm) row[mm] *= sinv;
    }
    __syncthreads();
    for (int jj = 0; jj < 8; ++jj) {
      int idx4 = t + 256 * jj; int row = idx4 >> 4, c4 = (idx4 & 15) * 4;
      int g = (bn0 + row) * 2048 + h * 64 + c4;
      *(float4*)&S[g] = *(const float4*)&sm[row * 68 + c4];
    }
    for (int i = 0; i < 32; ++i) {
      int n = ng * 32 + i;
      f32x4 w4 = *(const f32x4*)&sm[n * 68 + mb];
      f32x4 x0 = *(const f32x4*)&xv[n * 68 + db];
      f32x4 x1 = *(const f32x4*)&xv[n * 68 + db + 4];
      f32x4 x2 = *(const f32x4*)&xv[n * 68 + db + 8];
      f32x4 x3 = *(const f32x4*)&xv[n * 68 + db + 12];
      if ((lane >> 4) == 0) {
        nacc[0] += w4[0]; nacc[1] += w4[1]; nacc[2] += w4[2]; nacc[3] += w4[3];
      }
      #pragma unroll
      for (int mi = 0; mi < 4; ++mi) {
        float wm = w4[mi];
        f32x4 wv = (f32x4){wm, wm, wm, wm};
        acc4[mi][0] += wv * x0;
        acc4[mi][1] += wv * x1;
        acc4[mi][2] += wv * x2;
        acc4[mi][3] += wv * x3;
      }
    }
    __syncthreads();
  }
  // cross-wave combine through LDS (sm/xv dead now)
  float* red = lsh;                     // [4][4096]
  #pragma unroll
  for (int mi = 0; mi < 4; ++mi)
    #pragma unroll
    for (int q = 0; q < 4; ++q)
      *(f32x4*)&red[ng * 4096 + (mb + mi) * 64 + db + q * 4] = acc4[mi][q];
  __syncthreads();
  int c0 = t * 16;
  for (int j4 = 0; j4 < 4; ++j4) {
    int c = c0 + j4 * 4;
    f32x4 r0 = *(const f32x4*)&red[c];
    f32x4 r1 = *(const f32x4*)&red[4096 + c];
    f32x4 r2 = *(const f32x4*)&red[8192 + c];
    f32x4 r3 = *(const f32x4*)&red[12288 + c];
    f32x4 sum = (r0 + r1) + (r2 + r3);
    atomicAdd(&token[pair * 4096 + c + 0], sum[0]);
    atomicAdd(&token[pair * 4096 + c + 1], sum[1]);
    atomicAdd(&token[pair * 4096 + c + 2], sum[2]);
    atomicAdd(&token[pair * 4096 + c + 3], sum[3]);
  }
  if (lane < 16) {
    #pragma unroll
    for (int mi = 0; mi < 4; ++mi)
      atomicAdd(&norm[pair * 64 + mb + mi], nacc[mi]);
  }
}

// ------------- stage C -----------
__global__ __launch_bounds__(256) void k_stagec(const float* __restrict__ token,
                                                const float* __restrict__ norm,
                                                const float* __restrict__ proj,
                                                float* __restrict__ ost) {
  int pair = blockIdx.x; int h = pair & 15;
  __shared__ float st[64 * 68];
  __shared__ float qk[64 * 196];
  int t = threadIdx.x;
  for (int j = 0; j < 16; ++j) {
    int idx = t + 256 * j; int m = idx >> 6, d = idx & 63;
    st[m * 68 + d] = token[pair * 4096 + idx] / (norm[pair * 64 + m] + 1e-5f);
  }
  __syncthreads();
  for (int idx = t; idx < 64 * 192; idx += 256) {
    int m = idx / 192, e = idx % 192;
    float s = 0.f;
    const float* pr = &proj[h * 12288 + e];
    const float* sr = &st[m * 68];
    for (int d = 0; d < 64; ++d) s = fmaf(sr[d], pr[d * 192], s);
    qk[m * 196 + e] = s;
  }
  __syncthreads();
  if (t < 64) {
    const float* q = &qk[t * 196];
    float dots[64];
    float mx = -1e30f;
    for (int d = 0; d < 64; ++d) { dots[d] = q[d] * q[64 + d] * 0.125f; mx = fmaxf(mx, dots[d]); }
    float sum = 0.f;
    for (int d = 0; d < 64; ++d) { dots[d] = expf(dots[d] - mx); sum += dots[d]; }
    float sinv = 1.f / sum;
    for (int d = 0; d < 64; ++d) ost[pair * 4096 + t * 64 + d] = dots[d] * sinv * q[128 + d];
  }
}

// ------------- stage D (fallback: fp32 into S) -----------
__global__ __launch_bounds__(256) void k_staged(float* __restrict__ S, const float* __restrict__ ost) {
  int pair = blockIdx.x >> 6, chunk = blockIdx.x & 63;
  int b = pair >> 4, h = pair & 15;
  __shared__ float ws[128 * 68];
  int t = threadIdx.x;
  int bn0 = b * 8192 + chunk * 128;
  for (int jj = 0; jj < 8; ++jj) {
    int idx4 = t + 256 * jj; int row = idx4 >> 4, c4 = (idx4 & 15) * 4;
    *(float4*)&ws[row * 68 + c4] = *(const float4*)&S[(bn0 + row) * 2048 + h * 64 + c4];
  }
  int d = t & 63, ng = t >> 6;
  float o[64];
  #pragma unroll
  for (int mm = 0; mm < 64; ++mm) o[mm] = ost[pair * 4096 + mm * 64 + d];
  __syncthreads();
  for (int i = 0; i < 32; ++i) {
    int n = ng + 4 * i;
    const float* wr = &ws[n * 68];
    float s = 0.f;
    #pragma unroll
    for (int mm = 0; mm < 64; ++mm) s = fmaf(wr[mm], o[mm], s);
    S[(bn0 + n) * 2048 + 1024 + h * 64 + d] = s;
  }
}

// ------------- stage D (fast): register-blocked 2d x 16n per thread --------
// Round-12: thread (d2 = t&31 -> d = 2*d2,2*d2+1; ng = t>>5 -> 16 n).
// Per n: 16 b128 w-row reads shared by 2 d (was 1 d) -> VALU-bound.
// Wave covers 2 n per iteration; the two half-wave row addresses alias the
// same banks (2-way, free per m136).
__global__ __launch_bounds__(256) void k_staged_bf(const float* __restrict__ S,
                                                   const float* __restrict__ ost,
                                                   __hip_bfloat16* __restrict__ oxh,
                                                   __hip_bfloat16* __restrict__ oxl) {
  int pair = blockIdx.x >> 6, chunk = blockIdx.x & 63;
  int b = pair >> 4, hd = pair & 15;
  __shared__ float ws[128 * 68];
  int t = threadIdx.x;
  int d2 = t & 31, ng = t >> 5;
  int bn0 = b * 8192 + chunk * 128;
  for (int jj = 0; jj < 8; ++jj) {
    int idx4 = t + 256 * jj; int row = idx4 >> 4, c4 = (idx4 & 15) * 4;
    *(float4*)&ws[row * 68 + c4] = *(const float4*)&S[(bn0 + row) * 2048 + hd * 64 + c4];
  }
  float2 o2[64];
  #pragma unroll
  for (int mm = 0; mm < 64; ++mm)
    o2[mm] = *(const float2*)&ost[pair * 4096 + mm * 64 + 2 * d2];
  __syncthreads();
  for (int i = 0; i < 16; ++i) {
    int n = ng * 16 + i;
    float a0 = 0.f, a1 = 0.f;
    #pragma unroll
    for (int mq = 0; mq < 16; ++mq) {
      f32x4 wv = *(const f32x4*)&ws[n * 68 + mq * 4];
      a0 = fmaf(wv[0], o2[mq * 4 + 0].x, a0); a1 = fmaf(wv[0], o2[mq * 4 + 0].y, a1);
      a0 = fmaf(wv[1], o2[mq * 4 + 1].x, a0); a1 = fmaf(wv[1], o2[mq * 4 + 1].y, a1);
      a0 = fmaf(wv[2], o2[mq * 4 + 2].x, a0); a1 = fmaf(wv[2], o2[mq * 4 + 2].y, a1);
      a0 = fmaf(wv[3], o2[mq * 4 + 3].x, a0); a1 = fmaf(wv[3], o2[mq * 4 + 3].y, a1);
    }
    __hip_bfloat16 hb[2] __attribute__((aligned(4)));
    __hip_bfloat16 lb[2] __attribute__((aligned(4)));
    split1(a0, hb[0], lb[0]);
    split1(a1, hb[1], lb[1]);
    size_t oo = (size_t)(bn0 + n) * 1024 + hd * 64 + 2 * d2;
    *(uint*)&oxh[oo] = *(const uint*)hb;
    *(uint*)&oxl[oo] = *(const uint*)lb;
  }
}

extern "C" void kernel_launch(void* const* d_in, const int* in_sizes, int n_in,
                              void* d_out, int out_size, void* d_ws, size_t ws_size,
                              hipStream_t stream) {
  const float* x      = (const float*)d_in[0];
  const float* w_kv   = (const float*)d_in[2];
  const float* b_kv   = (const float*)d_in[3];
  const float* w_temp = (const float*)d_in[4];
  const float* b_temp = (const float*)d_in[5];
  const float* xq     = (const float*)d_in[6];
  const float* proj   = (const float*)d_in[7];
  const float* w_out  = (const float*)d_in[8];
  const float* b_out  = (const float*)d_in[9];
  float* out = (float*)d_out;

  float* ws    = (float*)d_ws;
  float* S     = ws;                       // [32768][2048] fp32
  float* T     = S + 67108864;             // [32768][16]
  float* BIAS1 = T + 524288;               // [2048]
  float* TOKEN = BIAS1 + 2048;             // 262144
  float* NORM  = TOKEN + 262144;           // 4096
  float* OST   = NORM + 4096;              // 262144
  float* FEND  = OST + 262144;
  __hip_bfloat16* WbTh = (__hip_bfloat16*)FEND;   // [2048][1024]
  __hip_bfloat16* WbTl = WbTh + 2097152;          // [2048][1024]
  __hip_bfloat16* WoTh = WbTl + 2097152;          // [1024][1024]
  __hip_bfloat16* WoTl = WoTh + 1048576;          // [1024][1024]
  __hip_bfloat16* XH   = WoTl + 1048576;          // [32768][1024] (reused as out_x hi)
  __hip_bfloat16* XL   = XH + 33554432;           // [32768][1024] (reused as out_x lo)
  const size_t need_fast = 419454976ULL;          // bytes

  hipMemsetAsync(TOKEN, 0, (262144 + 4096) * sizeof(float), stream);
  k_bias1<<<8, 256, 0, stream>>>(xq, b_kv, BIAS1);
  k_temp<<<2048, 256, 0, stream>>>(x, w_temp, b_temp, T);

  if (ws_size >= need_fast) {
    // ---- fast path: parity-paired 3-term 256x256 pipelined MFMA GEMMs ----
    k_acat_t<<<128, 256, 0, stream>>>(w_kv, xq, WbTh, WbTl);
    k_tsplit<<<dim3(16, 16), 256, 0, stream>>>(w_kv + 1024, 2048,
                                               WbTh + 1048576, WbTl + 1048576);
    k_tsplit<<<dim3(16, 16), 256, 0, stream>>>(w_out, 1024, WoTh, WoTl);
    k_split<<<16384, 256, 0, stream>>>(x, XH, XL);
    k_mfma8<<<dim3(8, 128), 512, 0, stream>>>(XH, XL, WbTh, WbTl, BIAS1, S, 2048);
    k_smax<<<512, 256, 0, stream>>>(S, T, TOKEN, NORM);
    k_stagec<<<64, 256, 0, stream>>>(TOKEN, NORM, proj, OST);
    k_staged_bf<<<4096, 256, 0, stream>>>(S, OST, XH, XL);
    k_mfma8<<<dim3(4, 128), 512, 0, stream>>>(XH, XL, WoTh, WoTl, b_out, out, 1024);
  } else {
    // ---- fallback: round-2 fp32 vector GEMMs ----
    float* WBIG = (float*)WbTh;            // [1024][2048] fp32 fits in WbTh+WbTl
    k_acat<<<128, 256, 0, stream>>>(w_kv, xq, WBIG);
    k_copyv<<<1024, 256, 0, stream>>>(w_kv, WBIG);
    k_gemm<<<dim3(16, 256), 256, 0, stream>>>(x, 1024, WBIG, 2048, BIAS1, S, 2048, 1024);
    k_smax<<<512, 256, 0, stream>>>(S, T, TOKEN, NORM);
    k_stagec<<<64, 256, 0, stream>>>(TOKEN, NORM, proj, OST);
    k_staged<<<4096, 256, 0, stream>>>(S, OST);
    k_gemm<<<dim3(8, 256), 256, 0, stream>>>(S + 1024, 2048, w_out, 1024, b_out, out, 1024, 1024);
  }
}